// Round 7
// baseline (531.037 us; speedup 1.0000x reference)
//
#include <hip/hip_runtime.h>
#include <cstdint>

#define RR 8
#define D0 128
#define D1 64
#define D2 32

typedef unsigned short u16;
typedef unsigned int u32;
typedef short short8 __attribute__((ext_vector_type(8)));
typedef float floatx4 __attribute__((ext_vector_type(4)));

static __device__ __forceinline__ float relu_f(float x) { return x > 0.f ? x : 0.f; }
static __device__ __forceinline__ float sigm_f(float x) { return 1.0f / (1.0f + __expf(-x)); }

static __device__ __forceinline__ u16 f2bf(float x) {
  unsigned int u = __float_as_uint(x);
  u += 0x7fffu + ((u >> 16) & 1u);   // RNE
  return (u16)(u >> 16);
}
static __device__ __forceinline__ float bf2f(u16 v) {
  return __uint_as_float(((unsigned int)v) << 16);
}

// ---- per-(dst,rel) counts ----
__global__ void count_k(const int* __restrict__ dst, const int* __restrict__ et,
                        int* __restrict__ counts, int E) {
  int e = blockIdx.x * 256 + threadIdx.x;
  if (e < E) atomicAdd(&counts[dst[e] * RR + et[e]], 1);
}

// per-d: invc for 8 rels + total degree
__global__ void invc_k(const int* __restrict__ counts, float* __restrict__ invc,
                       int* __restrict__ countd, int N) {
  int d = blockIdx.x * 256 + threadIdx.x;
  if (d >= N) return;
  int tot = 0;
#pragma unroll
  for (int r = 0; r < RR; ++r) {
    int c = counts[d * RR + r];
    tot += c;
    invc[d * RR + r] = 1.0f / (float)(c > 1 ? c : 1);
  }
  countd[d] = tot;
}

// ---- 3-kernel exclusive prefix scan over countd (1024 elems / block) ----
__global__ void scan1_k(const int* __restrict__ v, int* __restrict__ bsum, int n) {
  __shared__ int sd[256];
  int b = blockIdx.x, t = threadIdx.x;
  int base = b * 1024 + t * 4;
  int s = 0;
#pragma unroll
  for (int j = 0; j < 4; ++j) { int i = base + j; if (i < n) s += v[i]; }
  sd[t] = s; __syncthreads();
  for (int st = 128; st > 0; st >>= 1) { if (t < st) sd[t] += sd[t + st]; __syncthreads(); }
  if (t == 0) bsum[b] = sd[0];
}
__global__ void scan2_k(int* __restrict__ bsum, int nb) {
  if (threadIdx.x == 0 && blockIdx.x == 0) {
    int acc = 0;
    for (int i = 0; i < nb; ++i) { int t = bsum[i]; bsum[i] = acc; acc += t; }
  }
}
__global__ void scan3_k(const int* __restrict__ v, const int* __restrict__ bsum,
                        int* __restrict__ off, int n) {
  __shared__ int sd[256];
  int b = blockIdx.x, t = threadIdx.x;
  int base = b * 1024 + t * 4;
  int vals[4]; int s = 0; int loc[4];
#pragma unroll
  for (int j = 0; j < 4; ++j) {
    int i = base + j; int x = (i < n) ? v[i] : 0;
    vals[j] = x; loc[j] = s; s += x;
  }
  sd[t] = s; __syncthreads();
  for (int st = 1; st < 256; st <<= 1) {
    int x = (t >= st) ? sd[t - st] : 0;
    __syncthreads(); sd[t] += x; __syncthreads();
  }
  int texcl = sd[t] - s;
#pragma unroll
  for (int j = 0; j < 4; ++j) {
    int i = base + j;
    if (i < n) {
      off[i] = bsum[b] + texcl + loc[j];
      if (i == n - 1) off[n] = bsum[b] + texcl + loc[j] + vals[j];
    }
  }
}

// ---- counting-sort edges by dst: sorted_sr[p] = src*8 + rel ----
__global__ void permute_k(const int* __restrict__ src, const int* __restrict__ dst,
                          const int* __restrict__ et, const int* __restrict__ off,
                          int* __restrict__ cur, int* __restrict__ sorted_sr, int E) {
  int e = blockIdx.x * 256 + threadIdx.x;
  if (e >= E) return;
  int d = dst[e];
  int p = off[d] + atomicAdd(&cur[d], 1);
  sorted_sr[p] = src[e] * RR + et[e];
}

// ---- pack [W(r,k,o) | root(k,o)] -> BT[c][k] bf16 ----
__global__ void packBT_k(const float* __restrict__ W, const float* __restrict__ root,
                         u16* __restrict__ BT, int K, int FOUT, int NC, int YC) {
  int i = blockIdx.x * 256 + threadIdx.x;
  if (i >= NC * K) return;
  int c = i / K, k = i - c * K;
  float v;
  if (c < YC) { int r = c / FOUT, o = c - r * FOUT; v = W[((size_t)r * K + k) * FOUT + o]; }
  else        { int o = c - YC; v = root[(size_t)k * (NC - YC) + o]; }
  BT[(size_t)c * K + k] = f2bf(v);
}

// ---- bf16 MFMA GEMM, ROWS(=32)-row block, internal column-panel loop.
// A staged once in LDS (fp32->bf16 fused if AF32), preloaded to regs; per panel
// the B fragments are loaded together (MLP vs L2 latency) then MFMA.
// Operands swapped => lane&15 = row, quad*4+reg = 4 consecutive cols
// => packed uint2 (Y bf16x4) / float4 (Xroot) stores. K-order identical => Y bitwise same.
template <int K, int ROWS, bool AF32>
__global__ __launch_bounds__(256) void gemm_k(
    const void* __restrict__ Aptr, const u16* __restrict__ BT,
    const float* __restrict__ bias, u16* __restrict__ Y,
    float* __restrict__ Xroot, int N, int NC, int YC) {
  const int KP = K + 8;
  const int NK = K / 32;
  __shared__ __align__(16) u16 Al[ROWS * KP];
  const int tid = threadIdx.x;
  const int rowBlk = blockIdx.x;
  const int CH = K / 8;                       // 16B chunks per row

  if (AF32) {
    const float* A = (const float*)Aptr;
    for (int c = tid; c < ROWS * CH; c += 256) {
      int row = c / CH, kc = c - row * CH;
      int gr = rowBlk * ROWS + row; if (gr >= N) gr = N - 1;
      const float4* p = (const float4*)&A[(size_t)gr * K + kc * 8];
      float4 v0 = p[0], v1 = p[1];
      uint4 o;
      o.x = (u32)f2bf(v0.x) | ((u32)f2bf(v0.y) << 16);
      o.y = (u32)f2bf(v0.z) | ((u32)f2bf(v0.w) << 16);
      o.z = (u32)f2bf(v1.x) | ((u32)f2bf(v1.y) << 16);
      o.w = (u32)f2bf(v1.z) | ((u32)f2bf(v1.w) << 16);
      *(uint4*)&Al[row * KP + kc * 8] = o;
    }
  } else {
    const u16* A = (const u16*)Aptr;
    for (int c = tid; c < ROWS * CH; c += 256) {
      int row = c / CH, kc = c - row * CH;
      int gr = rowBlk * ROWS + row; if (gr >= N) gr = N - 1;
      *(uint4*)&Al[row * KP + kc * 8] = *(const uint4*)&A[(size_t)gr * K + kc * 8];
    }
  }
  __syncthreads();

  const int lane = tid & 63, wid = tid >> 6;
  const int l16 = lane & 15, quad = lane >> 4;
  const int wrow = (wid & 1) * 16;            // 2 row-halves of 32
  const int wcol = (wid >> 1) * 32;           // 2 col-halves of 64
  const int ROOTC = NC - YC;

  // A fragments: registers, loaded once, reused by every panel
  short8 af[NK];
#pragma unroll
  for (int ks = 0; ks < NK; ++ks) {
    int ko = ks * 32 + quad * 8;
    af[ks] = *(const short8*)&Al[(wrow + l16) * KP + ko];
  }

  for (int cb = 0; cb < NC; cb += 64) {
    int c0 = cb + wcol + l16;      if (c0 >= NC) c0 = NC - 1;
    int c1 = cb + wcol + 16 + l16; if (c1 >= NC) c1 = NC - 1;

    short8 bf0[NK], bf1[NK];
#pragma unroll
    for (int ks = 0; ks < NK; ++ks) {
      int ko = ks * 32 + quad * 8;
      bf0[ks] = *(const short8*)&BT[(size_t)c0 * K + ko];
      bf1[ks] = *(const short8*)&BT[(size_t)c1 * K + ko];
    }

    floatx4 acc[2] = {};   // [ni(col-half)]
#pragma unroll
    for (int ks = 0; ks < NK; ++ks) {
      acc[0] = __builtin_amdgcn_mfma_f32_16x16x32_bf16(bf0[ks], af[ks], acc[0], 0, 0, 0);
      acc[1] = __builtin_amdgcn_mfma_f32_16x16x32_bf16(bf1[ks], af[ks], acc[1], 0, 0, 0);
    }

    int r = rowBlk * ROWS + wrow + l16;
    if (r < N) {
#pragma unroll
      for (int ni = 0; ni < 2; ++ni) {
        int cbase = cb + wcol + ni * 16 + quad * 4;   // 4 consecutive cols in this lane
        floatx4 v = acc[ni];
        if (cbase < YC) {
          uint2 o;
          o.x = (u32)f2bf(v[0]) | ((u32)f2bf(v[1]) << 16);
          o.y = (u32)f2bf(v[2]) | ((u32)f2bf(v[3]) << 16);
          *(uint2*)&Y[(size_t)r * YC + cbase] = o;
        } else if (cbase < NC) {
          int o = cbase - YC;
          float4 w;
          w.x = v[0] + bias[o];     w.y = v[1] + bias[o + 1];
          w.z = v[2] + bias[o + 2]; w.w = v[3] + bias[o + 3];
          *(float4*)&Xroot[(size_t)r * ROOTC + o] = w;
        }
      }
    }
  }
}

// ---- layer-1 aggregation: one wave per dst, 8 edges in flight x uint4 (8 dims/lane),
// fused root+relu+bf16 pack ----
__global__ __launch_bounds__(256) void agg1_k(
    const int* __restrict__ off, const int* __restrict__ ssr,
    const uint4* __restrict__ Yu, const float* __restrict__ invc,
    const float4* __restrict__ xroot, uint4* __restrict__ X1b, int N) {
  int d = blockIdx.x * 4 + (threadIdx.x >> 6);
  if (d >= N) return;
  int lane = threadIdx.x & 63;
  int h = lane >> 3, fi = lane & 7;         // edge slot (8), dim group (8 dims)
  int beg = off[d], end = off[d + 1];
  float a0 = 0.f, a1 = 0.f, a2 = 0.f, a3 = 0.f, a4 = 0.f, a5 = 0.f, a6 = 0.f, a7 = 0.f;
  for (int i = beg + h; i < end; i += 8) {
    int sr = ssr[i];
    float w = invc[(d << 3) + (sr & 7)];
    uint4 y = Yu[(size_t)sr * 8 + fi];      // Y1 row = 64 bf16 = 8 uint4
    a0 = fmaf(bf2f((u16)y.x), w, a0); a1 = fmaf(bf2f((u16)(y.x >> 16)), w, a1);
    a2 = fmaf(bf2f((u16)y.y), w, a2); a3 = fmaf(bf2f((u16)(y.y >> 16)), w, a3);
    a4 = fmaf(bf2f((u16)y.z), w, a4); a5 = fmaf(bf2f((u16)(y.z >> 16)), w, a5);
    a6 = fmaf(bf2f((u16)y.w), w, a6); a7 = fmaf(bf2f((u16)(y.w >> 16)), w, a7);
  }
  // reduce over edge-slot bits (3,4,5 of lane)
#pragma unroll
  for (int m = 32; m >= 8; m >>= 1) {
    a0 += __shfl_xor(a0, m); a1 += __shfl_xor(a1, m);
    a2 += __shfl_xor(a2, m); a3 += __shfl_xor(a3, m);
    a4 += __shfl_xor(a4, m); a5 += __shfl_xor(a5, m);
    a6 += __shfl_xor(a6, m); a7 += __shfl_xor(a7, m);
  }
  if (h == 0) {
    float4 xr0 = xroot[(size_t)d * 16 + fi * 2];
    float4 xr1 = xroot[(size_t)d * 16 + fi * 2 + 1];
    uint4 o;
    o.x = (u32)f2bf(relu_f(xr0.x + a0)) | ((u32)f2bf(relu_f(xr0.y + a1)) << 16);
    o.y = (u32)f2bf(relu_f(xr0.z + a2)) | ((u32)f2bf(relu_f(xr0.w + a3)) << 16);
    o.z = (u32)f2bf(relu_f(xr1.x + a4)) | ((u32)f2bf(relu_f(xr1.y + a5)) << 16);
    o.w = (u32)f2bf(relu_f(xr1.z + a6)) | ((u32)f2bf(relu_f(xr1.w + a7)) << 16);
    X1b[(size_t)d * 8 + fi] = o;
  }
}

// ---- layer-2 aggregation: one wave per dst, 16 edges in flight x uint4 (8 dims/lane),
// fused root+sigmoid ----
__global__ __launch_bounds__(256) void agg2_k(
    const int* __restrict__ off, const int* __restrict__ ssr,
    const uint4* __restrict__ Yu, const float* __restrict__ invc,
    const float4* __restrict__ xroot, float4* __restrict__ out, int N) {
  int d = blockIdx.x * 4 + (threadIdx.x >> 6);
  if (d >= N) return;
  int lane = threadIdx.x & 63;
  int h = lane >> 2, fi = lane & 3;         // edge slot (16), dim group (8 dims)
  int beg = off[d], end = off[d + 1];
  float a0 = 0.f, a1 = 0.f, a2 = 0.f, a3 = 0.f, a4 = 0.f, a5 = 0.f, a6 = 0.f, a7 = 0.f;
  for (int i = beg + h; i < end; i += 16) {
    int sr = ssr[i];
    float w = invc[(d << 3) + (sr & 7)];
    uint4 y = Yu[(size_t)sr * 4 + fi];      // Y2 row = 32 bf16 = 4 uint4
    a0 = fmaf(bf2f((u16)y.x), w, a0); a1 = fmaf(bf2f((u16)(y.x >> 16)), w, a1);
    a2 = fmaf(bf2f((u16)y.y), w, a2); a3 = fmaf(bf2f((u16)(y.y >> 16)), w, a3);
    a4 = fmaf(bf2f((u16)y.z), w, a4); a5 = fmaf(bf2f((u16)(y.z >> 16)), w, a5);
    a6 = fmaf(bf2f((u16)y.w), w, a6); a7 = fmaf(bf2f((u16)(y.w >> 16)), w, a7);
  }
  // reduce over edge-slot bits (2,3,4,5 of lane)
#pragma unroll
  for (int m = 32; m >= 4; m >>= 1) {
    a0 += __shfl_xor(a0, m); a1 += __shfl_xor(a1, m);
    a2 += __shfl_xor(a2, m); a3 += __shfl_xor(a3, m);
    a4 += __shfl_xor(a4, m); a5 += __shfl_xor(a5, m);
    a6 += __shfl_xor(a6, m); a7 += __shfl_xor(a7, m);
  }
  if (h == 0) {
    float4 xr0 = xroot[(size_t)d * 8 + fi * 2];
    float4 xr1 = xroot[(size_t)d * 8 + fi * 2 + 1];
    float4 o1, o2;
    o1.x = sigm_f(xr0.x + a0); o1.y = sigm_f(xr0.y + a1);
    o1.z = sigm_f(xr0.z + a2); o1.w = sigm_f(xr0.w + a3);
    o2.x = sigm_f(xr1.x + a4); o2.y = sigm_f(xr1.y + a5);
    o2.z = sigm_f(xr1.z + a6); o2.w = sigm_f(xr1.w + a7);
    out[(size_t)d * 8 + fi * 2]     = o1;
    out[(size_t)d * 8 + fi * 2 + 1] = o2;
  }
}

extern "C" void kernel_launch(void* const* d_in, const int* in_sizes, int n_in,
                              void* d_out, int out_size, void* d_ws, size_t ws_size,
                              hipStream_t stream) {
  const int*   edge_index = (const int*)d_in[0];
  const int*   et    = (const int*)d_in[1];
  const float* emb   = (const float*)d_in[2];
  const float* W1    = (const float*)d_in[3];
  const float* root1 = (const float*)d_in[4];
  const float* b1    = (const float*)d_in[5];
  const float* W2    = (const float*)d_in[6];
  const float* root2 = (const float*)d_in[7];
  const float* b2    = (const float*)d_in[8];
  float* out = (float*)d_out;

  const int E = in_sizes[1];
  const int N = in_sizes[2] / D0;
  const int* src  = edge_index;
  const int* dstp = edge_index + E;

  char* ws = (char*)d_ws;
  size_t off_b = 0;
  auto alloc = [&](size_t bytes) { size_t o = off_b; off_b = (off_b + bytes + 255) & ~(size_t)255; return o; };
  int*   counts = (int*)(ws + alloc((size_t)N * RR * 4));
  int*   cur    = (int*)(ws + alloc((size_t)N * 4));
  float* invc   = (float*)(ws + alloc((size_t)N * RR * 4));
  int*   countd = (int*)(ws + alloc((size_t)N * 4));
  int*   offs   = (int*)(ws + alloc((size_t)(N + 1) * 4));
  int*   bsum   = (int*)(ws + alloc((size_t)1024 * 4));
  int*   ssr    = (int*)(ws + alloc((size_t)E * 4));
  u16*   X1b    = (u16*)(ws + alloc((size_t)N * D1 * 2));
  float* xr1    = (float*)(ws + alloc((size_t)N * D1 * 4));
  float* xr2    = (float*)(ws + alloc((size_t)N * D2 * 4));
  u16*   BT1    = (u16*)(ws + alloc((size_t)(RR * D1 + D1) * D0 * 2));
  u16*   BT2    = (u16*)(ws + alloc((size_t)(RR * D2 + D2) * D1 * 2 + 8192)); // +pad for clamp
  u16*   Y      = (u16*)(ws + alloc((size_t)N * RR * D1 * 2));   // Y1; reused as Y2

  auto cdiv = [](size_t a, size_t b) { return (unsigned)((a + b - 1) / b); };

  const int NC1 = RR * D1 + D1, YC1 = RR * D1;  // 576 / 512
  const int NC2 = RR * D2 + D2, YC2 = RR * D2;  // 288 / 256
  const int NB = cdiv(N, 1024);

  // ---- degree counts, invc, CSR offsets, counting sort ----
  hipMemsetAsync(counts, 0, (size_t)N * RR * 4, stream);
  hipMemsetAsync(cur, 0, (size_t)N * 4, stream);
  count_k<<<cdiv(E, 256), 256, 0, stream>>>(dstp, et, counts, E);
  invc_k<<<cdiv(N, 256), 256, 0, stream>>>(counts, invc, countd, N);
  scan1_k<<<NB, 256, 0, stream>>>(countd, bsum, N);
  scan2_k<<<1, 64, 0, stream>>>(bsum, NB);
  scan3_k<<<NB, 256, 0, stream>>>(countd, bsum, offs, N);
  permute_k<<<cdiv(E, 256), 256, 0, stream>>>(src, dstp, et, offs, cur, ssr, E);

  // ---- weight packing ----
  packBT_k<<<cdiv((size_t)NC1 * D0, 256), 256, 0, stream>>>(W1, root1, BT1, D0, D1, NC1, YC1);
  packBT_k<<<cdiv((size_t)NC2 * D1, 256), 256, 0, stream>>>(W2, root2, BT2, D1, D2, NC2, YC2);

  // ---- layer 1 (A = fp32 emb, convert fused into staging; 32-row blocks) ----
  gemm_k<D0, 32, true><<<cdiv(N, 32), 256, 0, stream>>>(emb, BT1, b1, Y, xr1, N, NC1, YC1);
  agg1_k<<<cdiv(N, 4), 256, 0, stream>>>(offs, ssr, (const uint4*)Y, invc,
                                         (const float4*)xr1, (uint4*)X1b, N);

  // ---- layer 2 (A = bf16 X1b; 32-row blocks) ----
  gemm_k<D1, 32, false><<<cdiv(N, 32), 256, 0, stream>>>(X1b, BT2, b2, Y, xr2, N, NC2, YC2);
  agg2_k<<<cdiv(N, 4), 256, 0, stream>>>(offs, ssr, (const uint4*)Y, invc,
                                         (const float4*)xr2, (float4*)out, N);
}

// Round 8
// 473.162 us; speedup vs baseline: 1.1223x; 1.1223x over previous
//
#include <hip/hip_runtime.h>
#include <cstdint>

#define RR 8
#define D0 128
#define D1 64
#define D2 32

typedef unsigned short u16;
typedef unsigned int u32;
typedef short short8 __attribute__((ext_vector_type(8)));
typedef float floatx4 __attribute__((ext_vector_type(4)));

static __device__ __forceinline__ float relu_f(float x) { return x > 0.f ? x : 0.f; }
static __device__ __forceinline__ float sigm_f(float x) { return 1.0f / (1.0f + __expf(-x)); }

static __device__ __forceinline__ u16 f2bf(float x) {
  unsigned int u = __float_as_uint(x);
  u += 0x7fffu + ((u >> 16) & 1u);   // RNE
  return (u16)(u >> 16);
}
static __device__ __forceinline__ float bf2f(u16 v) {
  return __uint_as_float(((unsigned int)v) << 16);
}

// ---- per-(dst,rel) counts ----
__global__ void count_k(const int* __restrict__ dst, const int* __restrict__ et,
                        int* __restrict__ counts, int E) {
  int e = blockIdx.x * 256 + threadIdx.x;
  if (e < E) atomicAdd(&counts[dst[e] * RR + et[e]], 1);
}

// per-d: invc for 8 rels + total degree
__global__ void invc_k(const int* __restrict__ counts, float* __restrict__ invc,
                       int* __restrict__ countd, int N) {
  int d = blockIdx.x * 256 + threadIdx.x;
  if (d >= N) return;
  int tot = 0;
#pragma unroll
  for (int r = 0; r < RR; ++r) {
    int c = counts[d * RR + r];
    tot += c;
    invc[d * RR + r] = 1.0f / (float)(c > 1 ? c : 1);
  }
  countd[d] = tot;
}

// ---- 3-kernel exclusive prefix scan over countd (1024 elems / block) ----
__global__ void scan1_k(const int* __restrict__ v, int* __restrict__ bsum, int n) {
  __shared__ int sd[256];
  int b = blockIdx.x, t = threadIdx.x;
  int base = b * 1024 + t * 4;
  int s = 0;
#pragma unroll
  for (int j = 0; j < 4; ++j) { int i = base + j; if (i < n) s += v[i]; }
  sd[t] = s; __syncthreads();
  for (int st = 128; st > 0; st >>= 1) { if (t < st) sd[t] += sd[t + st]; __syncthreads(); }
  if (t == 0) bsum[b] = sd[0];
}
// parallel exclusive scan of block sums (nb <= 256 fast path)
__global__ void scan2_k(int* __restrict__ bsum, int nb) {
  __shared__ int sd[256];
  int t = threadIdx.x;
  if (nb <= 256) {
    int v = (t < nb) ? bsum[t] : 0;
    sd[t] = v; __syncthreads();
    for (int st = 1; st < 256; st <<= 1) {
      int x = (t >= st) ? sd[t - st] : 0;
      __syncthreads(); sd[t] += x; __syncthreads();
    }
    if (t < nb) bsum[t] = sd[t] - v;
  } else if (t == 0) {
    int acc = 0;
    for (int i = 0; i < nb; ++i) { int tt = bsum[i]; bsum[i] = acc; acc += tt; }
  }
}
__global__ void scan3_k(const int* __restrict__ v, const int* __restrict__ bsum,
                        int* __restrict__ off, int n) {
  __shared__ int sd[256];
  int b = blockIdx.x, t = threadIdx.x;
  int base = b * 1024 + t * 4;
  int vals[4]; int s = 0; int loc[4];
#pragma unroll
  for (int j = 0; j < 4; ++j) {
    int i = base + j; int x = (i < n) ? v[i] : 0;
    vals[j] = x; loc[j] = s; s += x;
  }
  sd[t] = s; __syncthreads();
  for (int st = 1; st < 256; st <<= 1) {
    int x = (t >= st) ? sd[t - st] : 0;
    __syncthreads(); sd[t] += x; __syncthreads();
  }
  int texcl = sd[t] - s;
#pragma unroll
  for (int j = 0; j < 4; ++j) {
    int i = base + j;
    if (i < n) {
      off[i] = bsum[b] + texcl + loc[j];
      if (i == n - 1) off[n] = bsum[b] + texcl + loc[j] + vals[j];
    }
  }
}

// ---- counting-sort edges by dst: sorted_sr[p] = src*8 + rel ----
__global__ void permute_k(const int* __restrict__ src, const int* __restrict__ dst,
                          const int* __restrict__ et, const int* __restrict__ off,
                          int* __restrict__ cur, int* __restrict__ sorted_sr, int E) {
  int e = blockIdx.x * 256 + threadIdx.x;
  if (e >= E) return;
  int d = dst[e];
  int p = off[d] + atomicAdd(&cur[d], 1);
  sorted_sr[p] = src[e] * RR + et[e];
}

// ---- pack [W(r,k,o) | root(k,o)] -> BT[c][k] bf16 ----
__global__ void packBT_k(const float* __restrict__ W, const float* __restrict__ root,
                         u16* __restrict__ BT, int K, int FOUT, int NC, int YC) {
  int i = blockIdx.x * 256 + threadIdx.x;
  if (i >= NC * K) return;
  int c = i / K, k = i - c * K;
  float v;
  if (c < YC) { int r = c / FOUT, o = c - r * FOUT; v = W[((size_t)r * K + k) * FOUT + o]; }
  else        { int o = c - YC; v = root[(size_t)k * (NC - YC) + o]; }
  BT[(size_t)c * K + k] = f2bf(v);
}

// ---- bf16 MFMA GEMM (r6 structure): 64-row block, internal column-panel loop.
// A staged once in LDS (fp32->bf16 fused if AF32), preloaded to regs; per panel
// B fragments loaded together then MFMA. Swapped operands => lane&15 = row,
// quad*4+reg = 4 consecutive cols => packed uint2 / float4 stores.
template <int K, bool AF32>
__global__ __launch_bounds__(256) void gemm_k(
    const void* __restrict__ Aptr, const u16* __restrict__ BT,
    const float* __restrict__ bias, u16* __restrict__ Y,
    float* __restrict__ Xroot, int N, int NC, int YC) {
  const int KP = K + 8;
  const int NK = K / 32;
  __shared__ __align__(16) u16 Al[64 * KP];
  const int tid = threadIdx.x;
  const int rowBlk = blockIdx.x;
  const int CH = K / 8;

  if (AF32) {
    const float* A = (const float*)Aptr;
    for (int c = tid; c < 64 * CH; c += 256) {
      int row = c / CH, kc = c - row * CH;
      int gr = rowBlk * 64 + row; if (gr >= N) gr = N - 1;
      const float4* p = (const float4*)&A[(size_t)gr * K + kc * 8];
      float4 v0 = p[0], v1 = p[1];
      uint4 o;
      o.x = (u32)f2bf(v0.x) | ((u32)f2bf(v0.y) << 16);
      o.y = (u32)f2bf(v0.z) | ((u32)f2bf(v0.w) << 16);
      o.z = (u32)f2bf(v1.x) | ((u32)f2bf(v1.y) << 16);
      o.w = (u32)f2bf(v1.z) | ((u32)f2bf(v1.w) << 16);
      *(uint4*)&Al[row * KP + kc * 8] = o;
    }
  } else {
    const u16* A = (const u16*)Aptr;
    for (int c = tid; c < 64 * CH; c += 256) {
      int row = c / CH, kc = c - row * CH;
      int gr = rowBlk * 64 + row; if (gr >= N) gr = N - 1;
      *(uint4*)&Al[row * KP + kc * 8] = *(const uint4*)&A[(size_t)gr * K + kc * 8];
    }
  }
  __syncthreads();

  const int lane = tid & 63, wid = tid >> 6;
  const int l16 = lane & 15, quad = lane >> 4;
  const int wrow = (wid >> 1) * 32, wcol = (wid & 1) * 32;
  const int ROOTC = NC - YC;

  short8 af[2][NK];
#pragma unroll
  for (int ks = 0; ks < NK; ++ks) {
    int ko = ks * 32 + quad * 8;
    af[0][ks] = *(const short8*)&Al[(wrow +      l16) * KP + ko];
    af[1][ks] = *(const short8*)&Al[(wrow + 16 + l16) * KP + ko];
  }

  for (int cb = 0; cb < NC; cb += 64) {
    int c0 = cb + wcol + l16;      if (c0 >= NC) c0 = NC - 1;
    int c1 = cb + wcol + 16 + l16; if (c1 >= NC) c1 = NC - 1;

    short8 bf0[NK], bf1[NK];
#pragma unroll
    for (int ks = 0; ks < NK; ++ks) {
      int ko = ks * 32 + quad * 8;
      bf0[ks] = *(const short8*)&BT[(size_t)c0 * K + ko];
      bf1[ks] = *(const short8*)&BT[(size_t)c1 * K + ko];
    }

    floatx4 acc[2][2] = {};
#pragma unroll
    for (int ks = 0; ks < NK; ++ks) {
      acc[0][0] = __builtin_amdgcn_mfma_f32_16x16x32_bf16(bf0[ks], af[0][ks], acc[0][0], 0, 0, 0);
      acc[0][1] = __builtin_amdgcn_mfma_f32_16x16x32_bf16(bf1[ks], af[0][ks], acc[0][1], 0, 0, 0);
      acc[1][0] = __builtin_amdgcn_mfma_f32_16x16x32_bf16(bf0[ks], af[1][ks], acc[1][0], 0, 0, 0);
      acc[1][1] = __builtin_amdgcn_mfma_f32_16x16x32_bf16(bf1[ks], af[1][ks], acc[1][1], 0, 0, 0);
    }

#pragma unroll
    for (int mi = 0; mi < 2; ++mi) {
      int r = rowBlk * 64 + wrow + mi * 16 + l16;
      if (r >= N) continue;
#pragma unroll
      for (int ni = 0; ni < 2; ++ni) {
        int cbase = cb + wcol + ni * 16 + quad * 4;
        floatx4 v = acc[mi][ni];
        if (cbase < YC) {
          uint2 o;
          o.x = (u32)f2bf(v[0]) | ((u32)f2bf(v[1]) << 16);
          o.y = (u32)f2bf(v[2]) | ((u32)f2bf(v[3]) << 16);
          *(uint2*)&Y[(size_t)r * YC + cbase] = o;
        } else if (cbase < NC) {
          int o = cbase - YC;
          float4 w;
          w.x = v[0] + bias[o];     w.y = v[1] + bias[o + 1];
          w.z = v[2] + bias[o + 2]; w.w = v[3] + bias[o + 3];
          *(float4*)&Xroot[(size_t)r * ROOTC + o] = w;
        }
      }
    }
  }
}

// ---- layer-1 aggregation v2: one wave per dst. ssr[beg..beg+63] preloaded into
// lane registers (one coalesced load) and broadcast via shfl => no dependent
// index chain. 8 slots x 2 edges per group = 16 independent Y gathers in flight.
// Per-slot uniform guards => zero wasted gathers. deg>64 fallback loop.
__global__ __launch_bounds__(256) void agg1_k(
    const int* __restrict__ off, const int* __restrict__ ssr,
    const uint4* __restrict__ Yu, const float* __restrict__ invc,
    const float4* __restrict__ xroot, uint4* __restrict__ X1b, int N, int E) {
  int d = blockIdx.x * 4 + (threadIdx.x >> 6);
  if (d >= N) return;
  int lane = threadIdx.x & 63;
  int h = lane >> 3, fi = lane & 7;         // slot (8), dim group (8 bf16)
  int beg = off[d], end = off[d + 1];
  int deg = end - beg;
  int ei = beg + lane; if (ei >= E) ei = E - 1;
  int e = ssr[ei];                           // coalesced; clamped tail unused
  float a0 = 0.f, a1 = 0.f, a2 = 0.f, a3 = 0.f, a4 = 0.f, a5 = 0.f, a6 = 0.f, a7 = 0.f;
  int dcap = deg < 64 ? deg : 64;
  for (int jb = 0; jb < dcap; jb += 16) {
    int j0 = jb + h, j1 = jb + 8 + h;
    int sr0 = __shfl(e, j0);
    int sr1 = __shfl(e, j1);
    if (j0 < deg) {
      float w = invc[(d << 3) + (sr0 & 7)];
      uint4 y = Yu[(size_t)sr0 * 8 + fi];
      a0 = fmaf(bf2f((u16)y.x), w, a0); a1 = fmaf(bf2f((u16)(y.x >> 16)), w, a1);
      a2 = fmaf(bf2f((u16)y.y), w, a2); a3 = fmaf(bf2f((u16)(y.y >> 16)), w, a3);
      a4 = fmaf(bf2f((u16)y.z), w, a4); a5 = fmaf(bf2f((u16)(y.z >> 16)), w, a5);
      a6 = fmaf(bf2f((u16)y.w), w, a6); a7 = fmaf(bf2f((u16)(y.w >> 16)), w, a7);
    }
    if (j1 < deg) {
      float w = invc[(d << 3) + (sr1 & 7)];
      uint4 y = Yu[(size_t)sr1 * 8 + fi];
      a0 = fmaf(bf2f((u16)y.x), w, a0); a1 = fmaf(bf2f((u16)(y.x >> 16)), w, a1);
      a2 = fmaf(bf2f((u16)y.y), w, a2); a3 = fmaf(bf2f((u16)(y.y >> 16)), w, a3);
      a4 = fmaf(bf2f((u16)y.z), w, a4); a5 = fmaf(bf2f((u16)(y.z >> 16)), w, a5);
      a6 = fmaf(bf2f((u16)y.w), w, a6); a7 = fmaf(bf2f((u16)(y.w >> 16)), w, a7);
    }
  }
  if (deg > 64) {
    for (int i = beg + 64 + h; i < end; i += 8) {
      int sr = ssr[i];
      float w = invc[(d << 3) + (sr & 7)];
      uint4 y = Yu[(size_t)sr * 8 + fi];
      a0 = fmaf(bf2f((u16)y.x), w, a0); a1 = fmaf(bf2f((u16)(y.x >> 16)), w, a1);
      a2 = fmaf(bf2f((u16)y.y), w, a2); a3 = fmaf(bf2f((u16)(y.y >> 16)), w, a3);
      a4 = fmaf(bf2f((u16)y.z), w, a4); a5 = fmaf(bf2f((u16)(y.z >> 16)), w, a5);
      a6 = fmaf(bf2f((u16)y.w), w, a6); a7 = fmaf(bf2f((u16)(y.w >> 16)), w, a7);
    }
  }
#pragma unroll
  for (int m = 32; m >= 8; m >>= 1) {
    a0 += __shfl_xor(a0, m); a1 += __shfl_xor(a1, m);
    a2 += __shfl_xor(a2, m); a3 += __shfl_xor(a3, m);
    a4 += __shfl_xor(a4, m); a5 += __shfl_xor(a5, m);
    a6 += __shfl_xor(a6, m); a7 += __shfl_xor(a7, m);
  }
  if (h == 0) {
    float4 xr0 = xroot[(size_t)d * 16 + fi * 2];
    float4 xr1 = xroot[(size_t)d * 16 + fi * 2 + 1];
    uint4 o;
    o.x = (u32)f2bf(relu_f(xr0.x + a0)) | ((u32)f2bf(relu_f(xr0.y + a1)) << 16);
    o.y = (u32)f2bf(relu_f(xr0.z + a2)) | ((u32)f2bf(relu_f(xr0.w + a3)) << 16);
    o.z = (u32)f2bf(relu_f(xr1.x + a4)) | ((u32)f2bf(relu_f(xr1.y + a5)) << 16);
    o.w = (u32)f2bf(relu_f(xr1.z + a6)) | ((u32)f2bf(relu_f(xr1.w + a7)) << 16);
    X1b[(size_t)d * 8 + fi] = o;
  }
}

// ---- layer-2 aggregation v2: 16 slots x 2 edges per group = 32 gathers in flight ----
__global__ __launch_bounds__(256) void agg2_k(
    const int* __restrict__ off, const int* __restrict__ ssr,
    const uint4* __restrict__ Yu, const float* __restrict__ invc,
    const float4* __restrict__ xroot, float4* __restrict__ out, int N, int E) {
  int d = blockIdx.x * 4 + (threadIdx.x >> 6);
  if (d >= N) return;
  int lane = threadIdx.x & 63;
  int h = lane >> 2, fi = lane & 3;         // slot (16), dim group (8 bf16)
  int beg = off[d], end = off[d + 1];
  int deg = end - beg;
  int ei = beg + lane; if (ei >= E) ei = E - 1;
  int e = ssr[ei];
  float a0 = 0.f, a1 = 0.f, a2 = 0.f, a3 = 0.f, a4 = 0.f, a5 = 0.f, a6 = 0.f, a7 = 0.f;
  int dcap = deg < 64 ? deg : 64;
  for (int jb = 0; jb < dcap; jb += 32) {
    int j0 = jb + h, j1 = jb + 16 + h;
    int sr0 = __shfl(e, j0);
    int sr1 = __shfl(e, j1);
    if (j0 < deg) {
      float w = invc[(d << 3) + (sr0 & 7)];
      uint4 y = Yu[(size_t)sr0 * 4 + fi];
      a0 = fmaf(bf2f((u16)y.x), w, a0); a1 = fmaf(bf2f((u16)(y.x >> 16)), w, a1);
      a2 = fmaf(bf2f((u16)y.y), w, a2); a3 = fmaf(bf2f((u16)(y.y >> 16)), w, a3);
      a4 = fmaf(bf2f((u16)y.z), w, a4); a5 = fmaf(bf2f((u16)(y.z >> 16)), w, a5);
      a6 = fmaf(bf2f((u16)y.w), w, a6); a7 = fmaf(bf2f((u16)(y.w >> 16)), w, a7);
    }
    if (j1 < deg) {
      float w = invc[(d << 3) + (sr1 & 7)];
      uint4 y = Yu[(size_t)sr1 * 4 + fi];
      a0 = fmaf(bf2f((u16)y.x), w, a0); a1 = fmaf(bf2f((u16)(y.x >> 16)), w, a1);
      a2 = fmaf(bf2f((u16)y.y), w, a2); a3 = fmaf(bf2f((u16)(y.y >> 16)), w, a3);
      a4 = fmaf(bf2f((u16)y.z), w, a4); a5 = fmaf(bf2f((u16)(y.z >> 16)), w, a5);
      a6 = fmaf(bf2f((u16)y.w), w, a6); a7 = fmaf(bf2f((u16)(y.w >> 16)), w, a7);
    }
  }
  if (deg > 64) {
    for (int i = beg + 64 + h; i < end; i += 16) {
      int sr = ssr[i];
      float w = invc[(d << 3) + (sr & 7)];
      uint4 y = Yu[(size_t)sr * 4 + fi];
      a0 = fmaf(bf2f((u16)y.x), w, a0); a1 = fmaf(bf2f((u16)(y.x >> 16)), w, a1);
      a2 = fmaf(bf2f((u16)y.y), w, a2); a3 = fmaf(bf2f((u16)(y.y >> 16)), w, a3);
      a4 = fmaf(bf2f((u16)y.z), w, a4); a5 = fmaf(bf2f((u16)(y.z >> 16)), w, a5);
      a6 = fmaf(bf2f((u16)y.w), w, a6); a7 = fmaf(bf2f((u16)(y.w >> 16)), w, a7);
    }
  }
#pragma unroll
  for (int m = 32; m >= 4; m >>= 1) {
    a0 += __shfl_xor(a0, m); a1 += __shfl_xor(a1, m);
    a2 += __shfl_xor(a2, m); a3 += __shfl_xor(a3, m);
    a4 += __shfl_xor(a4, m); a5 += __shfl_xor(a5, m);
    a6 += __shfl_xor(a6, m); a7 += __shfl_xor(a7, m);
  }
  if (h == 0) {
    float4 xr0 = xroot[(size_t)d * 8 + fi * 2];
    float4 xr1 = xroot[(size_t)d * 8 + fi * 2 + 1];
    float4 o1, o2;
    o1.x = sigm_f(xr0.x + a0); o1.y = sigm_f(xr0.y + a1);
    o1.z = sigm_f(xr0.z + a2); o1.w = sigm_f(xr0.w + a3);
    o2.x = sigm_f(xr1.x + a4); o2.y = sigm_f(xr1.y + a5);
    o2.z = sigm_f(xr1.z + a6); o2.w = sigm_f(xr1.w + a7);
    out[(size_t)d * 8 + fi * 2]     = o1;
    out[(size_t)d * 8 + fi * 2 + 1] = o2;
  }
}

extern "C" void kernel_launch(void* const* d_in, const int* in_sizes, int n_in,
                              void* d_out, int out_size, void* d_ws, size_t ws_size,
                              hipStream_t stream) {
  const int*   edge_index = (const int*)d_in[0];
  const int*   et    = (const int*)d_in[1];
  const float* emb   = (const float*)d_in[2];
  const float* W1    = (const float*)d_in[3];
  const float* root1 = (const float*)d_in[4];
  const float* b1    = (const float*)d_in[5];
  const float* W2    = (const float*)d_in[6];
  const float* root2 = (const float*)d_in[7];
  const float* b2    = (const float*)d_in[8];
  float* out = (float*)d_out;

  const int E = in_sizes[1];
  const int N = in_sizes[2] / D0;
  const int* src  = edge_index;
  const int* dstp = edge_index + E;

  char* ws = (char*)d_ws;
  size_t off_b = 0;
  auto alloc = [&](size_t bytes) { size_t o = off_b; off_b = (off_b + bytes + 255) & ~(size_t)255; return o; };
  int*   counts = (int*)(ws + alloc((size_t)N * RR * 4));
  int*   cur    = (int*)(ws + alloc((size_t)N * 4));
  float* invc   = (float*)(ws + alloc((size_t)N * RR * 4));
  int*   countd = (int*)(ws + alloc((size_t)N * 4));
  int*   offs   = (int*)(ws + alloc((size_t)(N + 1) * 4));
  int*   bsum   = (int*)(ws + alloc((size_t)1024 * 4));
  int*   ssr    = (int*)(ws + alloc((size_t)E * 4));
  u16*   X1b    = (u16*)(ws + alloc((size_t)N * D1 * 2));
  float* xr1    = (float*)(ws + alloc((size_t)N * D1 * 4));
  float* xr2    = (float*)(ws + alloc((size_t)N * D2 * 4));
  u16*   BT1    = (u16*)(ws + alloc((size_t)(RR * D1 + D1) * D0 * 2));
  u16*   BT2    = (u16*)(ws + alloc((size_t)(RR * D2 + D2) * D1 * 2 + 8192)); // +pad for clamp
  u16*   Y      = (u16*)(ws + alloc((size_t)N * RR * D1 * 2));   // Y1; reused as Y2

  auto cdiv = [](size_t a, size_t b) { return (unsigned)((a + b - 1) / b); };

  const int NC1 = RR * D1 + D1, YC1 = RR * D1;  // 576 / 512
  const int NC2 = RR * D2 + D2, YC2 = RR * D2;  // 288 / 256
  const int NB = cdiv(N, 1024);

  // ---- degree counts, invc, CSR offsets, counting sort ----
  hipMemsetAsync(counts, 0, (size_t)N * RR * 4, stream);
  hipMemsetAsync(cur, 0, (size_t)N * 4, stream);
  count_k<<<cdiv(E, 256), 256, 0, stream>>>(dstp, et, counts, E);
  invc_k<<<cdiv(N, 256), 256, 0, stream>>>(counts, invc, countd, N);
  scan1_k<<<NB, 256, 0, stream>>>(countd, bsum, N);
  scan2_k<<<1, 256, 0, stream>>>(bsum, NB);
  scan3_k<<<NB, 256, 0, stream>>>(countd, bsum, offs, N);
  permute_k<<<cdiv(E, 256), 256, 0, stream>>>(src, dstp, et, offs, cur, ssr, E);

  // ---- weight packing ----
  packBT_k<<<cdiv((size_t)NC1 * D0, 256), 256, 0, stream>>>(W1, root1, BT1, D0, D1, NC1, YC1);
  packBT_k<<<cdiv((size_t)NC2 * D1, 256), 256, 0, stream>>>(W2, root2, BT2, D1, D2, NC2, YC2);

  // ---- layer 1 (A = fp32 emb, convert fused into staging) ----
  gemm_k<D0, true><<<cdiv(N, 64), 256, 0, stream>>>(emb, BT1, b1, Y, xr1, N, NC1, YC1);
  agg1_k<<<cdiv(N, 4), 256, 0, stream>>>(offs, ssr, (const uint4*)Y, invc,
                                         (const float4*)xr1, (uint4*)X1b, N, E);

  // ---- layer 2 (A = bf16 X1b) ----
  gemm_k<D1, false><<<cdiv(N, 64), 256, 0, stream>>>(X1b, BT2, b2, Y, xr2, N, NC2, YC2);
  agg2_k<<<cdiv(N, 4), 256, 0, stream>>>(offs, ssr, (const uint4*)Y, invc,
                                         (const float4*)xr2, (float4*)out, N, E);
}

// Round 9
// 430.509 us; speedup vs baseline: 1.2335x; 1.0991x over previous
//
#include <hip/hip_runtime.h>
#include <cstdint>

#define RR 8
#define D0 128
#define D1 64
#define D2 32

typedef unsigned short u16;
typedef unsigned int u32;
typedef short short8 __attribute__((ext_vector_type(8)));
typedef float floatx4 __attribute__((ext_vector_type(4)));

static __device__ __forceinline__ float relu_f(float x) { return x > 0.f ? x : 0.f; }
static __device__ __forceinline__ float sigm_f(float x) { return 1.0f / (1.0f + __expf(-x)); }

static __device__ __forceinline__ u16 f2bf(float x) {
  unsigned int u = __float_as_uint(x);
  u += 0x7fffu + ((u >> 16) & 1u);   // RNE
  return (u16)(u >> 16);
}
static __device__ __forceinline__ float bf2f(u16 v) {
  return __uint_as_float(((unsigned int)v) << 16);
}

// ---- pack [W(r,k,o) | root(k,o)] -> BT[c][k] bf16 (shared body) ----
static __device__ __forceinline__ void packBT_body(
    const float* __restrict__ W, const float* __restrict__ root,
    u16* __restrict__ BT, int K, int FOUT, int NC, int YC, int i) {
  if (i >= NC * K) return;
  int c = i / K, k = i - c * K;
  float v;
  if (c < YC) { int r = c / FOUT, o = c - r * FOUT; v = W[((size_t)r * K + k) * FOUT + o]; }
  else        { int o = c - YC; v = root[(size_t)k * (NC - YC) + o]; }
  BT[(size_t)c * K + k] = f2bf(v);
}

// ---- merged: edge counting + both weight packs (independent jobs, one launch) ----
__global__ __launch_bounds__(256) void prep_k(
    const int* __restrict__ dstp, const int* __restrict__ et, int* __restrict__ counts, int E,
    const float* __restrict__ W1, const float* __restrict__ root1, u16* __restrict__ BT1,
    const float* __restrict__ W2, const float* __restrict__ root2, u16* __restrict__ BT2,
    int nbCount, int nbP1) {
  int b = blockIdx.x;
  if (b < nbCount) {
    int e = b * 256 + threadIdx.x;
    if (e < E) atomicAdd(&counts[dstp[e] * RR + et[e]], 1);
  } else if (b < nbCount + nbP1) {
    packBT_body(W1, root1, BT1, D0, D1, RR * D1 + D1, RR * D1, (b - nbCount) * 256 + threadIdx.x);
  } else {
    packBT_body(W2, root2, BT2, D1, D2, RR * D2 + D2, RR * D2, (b - nbCount - nbP1) * 256 + threadIdx.x);
  }
}

// ---- fused invc + per-block degree sums (scan stage 1) ----
__global__ __launch_bounds__(256) void invscan_k(
    const int* __restrict__ counts, float* __restrict__ invc,
    int* __restrict__ countd, int* __restrict__ bsum, int N) {
  __shared__ int sd[256];
  int b = blockIdx.x, t = threadIdx.x;
  int base = b * 1024 + t * 4;
  int s = 0;
  for (int j = 0; j < 4; ++j) {
    int d = base + j;
    if (d < N) {
      int tot = 0;
#pragma unroll
      for (int r = 0; r < RR; ++r) {
        int c = counts[d * RR + r];
        tot += c;
        invc[d * RR + r] = 1.0f / (float)(c > 1 ? c : 1);
      }
      countd[d] = tot;
      s += tot;
    }
  }
  sd[t] = s; __syncthreads();
  for (int st = 128; st > 0; st >>= 1) { if (t < st) sd[t] += sd[t + st]; __syncthreads(); }
  if (t == 0) bsum[b] = sd[0];
}

// parallel exclusive scan of block sums (nb <= 256 fast path)
__global__ void scan2_k(int* __restrict__ bsum, int nb) {
  __shared__ int sd[256];
  int t = threadIdx.x;
  if (nb <= 256) {
    int v = (t < nb) ? bsum[t] : 0;
    sd[t] = v; __syncthreads();
    for (int st = 1; st < 256; st <<= 1) {
      int x = (t >= st) ? sd[t - st] : 0;
      __syncthreads(); sd[t] += x; __syncthreads();
    }
    if (t < nb) bsum[t] = sd[t] - v;
  } else if (t == 0) {
    int acc = 0;
    for (int i = 0; i < nb; ++i) { int tt = bsum[i]; bsum[i] = acc; acc += tt; }
  }
}

__global__ void scan3_k(const int* __restrict__ v, const int* __restrict__ bsum,
                        int* __restrict__ off, int n) {
  __shared__ int sd[256];
  int b = blockIdx.x, t = threadIdx.x;
  int base = b * 1024 + t * 4;
  int vals[4]; int s = 0; int loc[4];
#pragma unroll
  for (int j = 0; j < 4; ++j) {
    int i = base + j; int x = (i < n) ? v[i] : 0;
    vals[j] = x; loc[j] = s; s += x;
  }
  sd[t] = s; __syncthreads();
  for (int st = 1; st < 256; st <<= 1) {
    int x = (t >= st) ? sd[t - st] : 0;
    __syncthreads(); sd[t] += x; __syncthreads();
  }
  int texcl = sd[t] - s;
#pragma unroll
  for (int j = 0; j < 4; ++j) {
    int i = base + j;
    if (i < n) {
      off[i] = bsum[b] + texcl + loc[j];
      if (i == n - 1) off[n] = bsum[b] + texcl + loc[j] + vals[j];
    }
  }
}

// ---- bf16 MFMA GEMM body: 64-row block, internal panel loop, A staged once.
// Epilogue: acc -> LDS tile (double-buffered) -> cooperative full-line uint4
// stores (8 lanes cover one 128B line per instruction). Y bitwise same as r8.
template <int K, bool AF32>
static __device__ __forceinline__ void gemm_body(
    const void* __restrict__ Aptr, const u16* __restrict__ BT,
    const float* __restrict__ bias, u16* __restrict__ Y,
    float* __restrict__ Xroot, int N, int NC, int YC, int rowBlk) {
  const int KP = K + 8;
  const int NK = K / 32;
  const int YTS = 72;                         // Yt row stride (bf16), 16B-aligned
  __shared__ __align__(16) u16 Al[64 * KP];
  __shared__ __align__(16) u16 Yt[2][64 * YTS];
  const int tid = threadIdx.x;
  const int CH = K / 8;

  if (AF32) {
    const float* A = (const float*)Aptr;
    for (int c = tid; c < 64 * CH; c += 256) {
      int row = c / CH, kc = c - row * CH;
      int gr = rowBlk * 64 + row; if (gr >= N) gr = N - 1;
      const float4* p = (const float4*)&A[(size_t)gr * K + kc * 8];
      float4 v0 = p[0], v1 = p[1];
      uint4 o;
      o.x = (u32)f2bf(v0.x) | ((u32)f2bf(v0.y) << 16);
      o.y = (u32)f2bf(v0.z) | ((u32)f2bf(v0.w) << 16);
      o.z = (u32)f2bf(v1.x) | ((u32)f2bf(v1.y) << 16);
      o.w = (u32)f2bf(v1.z) | ((u32)f2bf(v1.w) << 16);
      *(uint4*)&Al[row * KP + kc * 8] = o;
    }
  } else {
    const u16* A = (const u16*)Aptr;
    for (int c = tid; c < 64 * CH; c += 256) {
      int row = c / CH, kc = c - row * CH;
      int gr = rowBlk * 64 + row; if (gr >= N) gr = N - 1;
      *(uint4*)&Al[row * KP + kc * 8] = *(const uint4*)&A[(size_t)gr * K + kc * 8];
    }
  }
  __syncthreads();

  const int lane = tid & 63, wid = tid >> 6;
  const int l16 = lane & 15, quad = lane >> 4;
  const int wrow = (wid >> 1) * 32, wcol = (wid & 1) * 32;
  const int ROOTC = NC - YC;

  short8 af[2][NK];
#pragma unroll
  for (int ks = 0; ks < NK; ++ks) {
    int ko = ks * 32 + quad * 8;
    af[0][ks] = *(const short8*)&Al[(wrow +      l16) * KP + ko];
    af[1][ks] = *(const short8*)&Al[(wrow + 16 + l16) * KP + ko];
  }

  int p = 0;
  for (int cb = 0; cb < NC; cb += 64, ++p) {
    int c0 = cb + wcol + l16;      if (c0 >= NC) c0 = NC - 1;
    int c1 = cb + wcol + 16 + l16; if (c1 >= NC) c1 = NC - 1;

    short8 bf0[NK], bf1[NK];
#pragma unroll
    for (int ks = 0; ks < NK; ++ks) {
      int ko = ks * 32 + quad * 8;
      bf0[ks] = *(const short8*)&BT[(size_t)c0 * K + ko];
      bf1[ks] = *(const short8*)&BT[(size_t)c1 * K + ko];
    }

    floatx4 acc[2][2] = {};
#pragma unroll
    for (int ks = 0; ks < NK; ++ks) {
      acc[0][0] = __builtin_amdgcn_mfma_f32_16x16x32_bf16(bf0[ks], af[0][ks], acc[0][0], 0, 0, 0);
      acc[0][1] = __builtin_amdgcn_mfma_f32_16x16x32_bf16(bf1[ks], af[0][ks], acc[0][1], 0, 0, 0);
      acc[1][0] = __builtin_amdgcn_mfma_f32_16x16x32_bf16(bf0[ks], af[1][ks], acc[1][0], 0, 0, 0);
      acc[1][1] = __builtin_amdgcn_mfma_f32_16x16x32_bf16(bf1[ks], af[1][ks], acc[1][1], 0, 0, 0);
    }

    bool ypanel = (cb + 64) <= YC;    // YC is a multiple of 64 => panels never mixed
    if (ypanel) {
      u16* yt = Yt[p & 1];
#pragma unroll
      for (int mi = 0; mi < 2; ++mi)
#pragma unroll
        for (int ni = 0; ni < 2; ++ni) {
          floatx4 v = acc[mi][ni];
          uint2 o;
          o.x = (u32)f2bf(v[0]) | ((u32)f2bf(v[1]) << 16);
          o.y = (u32)f2bf(v[2]) | ((u32)f2bf(v[3]) << 16);
          *(uint2*)&yt[(wrow + mi * 16 + l16) * YTS + wcol + ni * 16 + quad * 4] = o;
        }
    } else {
#pragma unroll
      for (int mi = 0; mi < 2; ++mi) {
        int r = rowBlk * 64 + wrow + mi * 16 + l16;
        if (r >= N) continue;
#pragma unroll
        for (int ni = 0; ni < 2; ++ni) {
          int cbase = cb + wcol + ni * 16 + quad * 4;
          floatx4 v = acc[mi][ni];
          if (cbase >= YC && cbase < NC) {
            int o = cbase - YC;
            float4 w;
            w.x = v[0] + bias[o];     w.y = v[1] + bias[o + 1];
            w.z = v[2] + bias[o + 2]; w.w = v[3] + bias[o + 3];
            *(float4*)&Xroot[(size_t)r * ROOTC + o] = w;
          }
        }
      }
    }
    __syncthreads();
    if (ypanel) {
      const u16* yt = Yt[p & 1];
#pragma unroll
      for (int u = tid; u < 512; u += 256) {
        int row = u >> 3, cg = u & 7;
        int gr = rowBlk * 64 + row;
        if (gr < N)
          *(uint4*)&Y[(size_t)gr * YC + cb + cg * 8] = *(const uint4*)&yt[row * YTS + cg * 8];
      }
    }
  }
}

template <int K, bool AF32>
__global__ __launch_bounds__(256) void gemm_k(
    const void* __restrict__ Aptr, const u16* __restrict__ BT,
    const float* __restrict__ bias, u16* __restrict__ Y,
    float* __restrict__ Xroot, int N, int NC, int YC) {
  gemm_body<K, AF32>(Aptr, BT, bias, Y, Xroot, N, NC, YC, blockIdx.x);
}

// ---- merged: gemm layer-1 + edge permute (independent; overlap in one launch) ----
__global__ __launch_bounds__(256) void pg1_k(
    const void* __restrict__ emb, const u16* __restrict__ BT1, const float* __restrict__ b1,
    u16* __restrict__ Y, float* __restrict__ xr1, int N, int NC, int YC, int nbGemm,
    const int* __restrict__ src, const int* __restrict__ dstp, const int* __restrict__ et,
    const int* __restrict__ offs, int* __restrict__ cur, int* __restrict__ ssr, int E) {
  if ((int)blockIdx.x < nbGemm) {
    gemm_body<D0, true>(emb, BT1, b1, Y, xr1, N, NC, YC, blockIdx.x);
  } else {
    int e = (blockIdx.x - nbGemm) * 256 + threadIdx.x;
    if (e < E) {
      int d = dstp[e];
      int p = offs[d] + atomicAdd(&cur[d], 1);
      ssr[p] = src[e] * RR + et[e];
    }
  }
}

// ---- layer-1 aggregation (r8 v2): ssr block preloaded + shfl broadcast; 16 gathers in flight ----
__global__ __launch_bounds__(256) void agg1_k(
    const int* __restrict__ off, const int* __restrict__ ssr,
    const uint4* __restrict__ Yu, const float* __restrict__ invc,
    const float4* __restrict__ xroot, uint4* __restrict__ X1b, int N, int E) {
  int d = blockIdx.x * 4 + (threadIdx.x >> 6);
  if (d >= N) return;
  int lane = threadIdx.x & 63;
  int h = lane >> 3, fi = lane & 7;
  int beg = off[d], end = off[d + 1];
  int deg = end - beg;
  int ei = beg + lane; if (ei >= E) ei = E - 1;
  int e = ssr[ei];
  float a0 = 0.f, a1 = 0.f, a2 = 0.f, a3 = 0.f, a4 = 0.f, a5 = 0.f, a6 = 0.f, a7 = 0.f;
  int dcap = deg < 64 ? deg : 64;
  for (int jb = 0; jb < dcap; jb += 16) {
    int j0 = jb + h, j1 = jb + 8 + h;
    int sr0 = __shfl(e, j0);
    int sr1 = __shfl(e, j1);
    if (j0 < deg) {
      float w = invc[(d << 3) + (sr0 & 7)];
      uint4 y = Yu[(size_t)sr0 * 8 + fi];
      a0 = fmaf(bf2f((u16)y.x), w, a0); a1 = fmaf(bf2f((u16)(y.x >> 16)), w, a1);
      a2 = fmaf(bf2f((u16)y.y), w, a2); a3 = fmaf(bf2f((u16)(y.y >> 16)), w, a3);
      a4 = fmaf(bf2f((u16)y.z), w, a4); a5 = fmaf(bf2f((u16)(y.z >> 16)), w, a5);
      a6 = fmaf(bf2f((u16)y.w), w, a6); a7 = fmaf(bf2f((u16)(y.w >> 16)), w, a7);
    }
    if (j1 < deg) {
      float w = invc[(d << 3) + (sr1 & 7)];
      uint4 y = Yu[(size_t)sr1 * 8 + fi];
      a0 = fmaf(bf2f((u16)y.x), w, a0); a1 = fmaf(bf2f((u16)(y.x >> 16)), w, a1);
      a2 = fmaf(bf2f((u16)y.y), w, a2); a3 = fmaf(bf2f((u16)(y.y >> 16)), w, a3);
      a4 = fmaf(bf2f((u16)y.z), w, a4); a5 = fmaf(bf2f((u16)(y.z >> 16)), w, a5);
      a6 = fmaf(bf2f((u16)y.w), w, a6); a7 = fmaf(bf2f((u16)(y.w >> 16)), w, a7);
    }
  }
  if (deg > 64) {
    for (int i = beg + 64 + h; i < end; i += 8) {
      int sr = ssr[i];
      float w = invc[(d << 3) + (sr & 7)];
      uint4 y = Yu[(size_t)sr * 8 + fi];
      a0 = fmaf(bf2f((u16)y.x), w, a0); a1 = fmaf(bf2f((u16)(y.x >> 16)), w, a1);
      a2 = fmaf(bf2f((u16)y.y), w, a2); a3 = fmaf(bf2f((u16)(y.y >> 16)), w, a3);
      a4 = fmaf(bf2f((u16)y.z), w, a4); a5 = fmaf(bf2f((u16)(y.z >> 16)), w, a5);
      a6 = fmaf(bf2f((u16)y.w), w, a6); a7 = fmaf(bf2f((u16)(y.w >> 16)), w, a7);
    }
  }
#pragma unroll
  for (int m = 32; m >= 8; m >>= 1) {
    a0 += __shfl_xor(a0, m); a1 += __shfl_xor(a1, m);
    a2 += __shfl_xor(a2, m); a3 += __shfl_xor(a3, m);
    a4 += __shfl_xor(a4, m); a5 += __shfl_xor(a5, m);
    a6 += __shfl_xor(a6, m); a7 += __shfl_xor(a7, m);
  }
  if (h == 0) {
    float4 xr0 = xroot[(size_t)d * 16 + fi * 2];
    float4 xr1 = xroot[(size_t)d * 16 + fi * 2 + 1];
    uint4 o;
    o.x = (u32)f2bf(relu_f(xr0.x + a0)) | ((u32)f2bf(relu_f(xr0.y + a1)) << 16);
    o.y = (u32)f2bf(relu_f(xr0.z + a2)) | ((u32)f2bf(relu_f(xr0.w + a3)) << 16);
    o.z = (u32)f2bf(relu_f(xr1.x + a4)) | ((u32)f2bf(relu_f(xr1.y + a5)) << 16);
    o.w = (u32)f2bf(relu_f(xr1.z + a6)) | ((u32)f2bf(relu_f(xr1.w + a7)) << 16);
    X1b[(size_t)d * 8 + fi] = o;
  }
}

// ---- layer-2 aggregation (r8 v2): 32 gathers in flight ----
__global__ __launch_bounds__(256) void agg2_k(
    const int* __restrict__ off, const int* __restrict__ ssr,
    const uint4* __restrict__ Yu, const float* __restrict__ invc,
    const float4* __restrict__ xroot, float4* __restrict__ out, int N, int E) {
  int d = blockIdx.x * 4 + (threadIdx.x >> 6);
  if (d >= N) return;
  int lane = threadIdx.x & 63;
  int h = lane >> 2, fi = lane & 3;
  int beg = off[d], end = off[d + 1];
  int deg = end - beg;
  int ei = beg + lane; if (ei >= E) ei = E - 1;
  int e = ssr[ei];
  float a0 = 0.f, a1 = 0.f, a2 = 0.f, a3 = 0.f, a4 = 0.f, a5 = 0.f, a6 = 0.f, a7 = 0.f;
  int dcap = deg < 64 ? deg : 64;
  for (int jb = 0; jb < dcap; jb += 32) {
    int j0 = jb + h, j1 = jb + 16 + h;
    int sr0 = __shfl(e, j0);
    int sr1 = __shfl(e, j1);
    if (j0 < deg) {
      float w = invc[(d << 3) + (sr0 & 7)];
      uint4 y = Yu[(size_t)sr0 * 4 + fi];
      a0 = fmaf(bf2f((u16)y.x), w, a0); a1 = fmaf(bf2f((u16)(y.x >> 16)), w, a1);
      a2 = fmaf(bf2f((u16)y.y), w, a2); a3 = fmaf(bf2f((u16)(y.y >> 16)), w, a3);
      a4 = fmaf(bf2f((u16)y.z), w, a4); a5 = fmaf(bf2f((u16)(y.z >> 16)), w, a5);
      a6 = fmaf(bf2f((u16)y.w), w, a6); a7 = fmaf(bf2f((u16)(y.w >> 16)), w, a7);
    }
    if (j1 < deg) {
      float w = invc[(d << 3) + (sr1 & 7)];
      uint4 y = Yu[(size_t)sr1 * 4 + fi];
      a0 = fmaf(bf2f((u16)y.x), w, a0); a1 = fmaf(bf2f((u16)(y.x >> 16)), w, a1);
      a2 = fmaf(bf2f((u16)y.y), w, a2); a3 = fmaf(bf2f((u16)(y.y >> 16)), w, a3);
      a4 = fmaf(bf2f((u16)y.z), w, a4); a5 = fmaf(bf2f((u16)(y.z >> 16)), w, a5);
      a6 = fmaf(bf2f((u16)y.w), w, a6); a7 = fmaf(bf2f((u16)(y.w >> 16)), w, a7);
    }
  }
  if (deg > 64) {
    for (int i = beg + 64 + h; i < end; i += 16) {
      int sr = ssr[i];
      float w = invc[(d << 3) + (sr & 7)];
      uint4 y = Yu[(size_t)sr * 4 + fi];
      a0 = fmaf(bf2f((u16)y.x), w, a0); a1 = fmaf(bf2f((u16)(y.x >> 16)), w, a1);
      a2 = fmaf(bf2f((u16)y.y), w, a2); a3 = fmaf(bf2f((u16)(y.y >> 16)), w, a3);
      a4 = fmaf(bf2f((u16)y.z), w, a4); a5 = fmaf(bf2f((u16)(y.z >> 16)), w, a5);
      a6 = fmaf(bf2f((u16)y.w), w, a6); a7 = fmaf(bf2f((u16)(y.w >> 16)), w, a7);
    }
  }
#pragma unroll
  for (int m = 32; m >= 4; m >>= 1) {
    a0 += __shfl_xor(a0, m); a1 += __shfl_xor(a1, m);
    a2 += __shfl_xor(a2, m); a3 += __shfl_xor(a3, m);
    a4 += __shfl_xor(a4, m); a5 += __shfl_xor(a5, m);
    a6 += __shfl_xor(a6, m); a7 += __shfl_xor(a7, m);
  }
  if (h == 0) {
    float4 xr0 = xroot[(size_t)d * 8 + fi * 2];
    float4 xr1 = xroot[(size_t)d * 8 + fi * 2 + 1];
    float4 o1, o2;
    o1.x = sigm_f(xr0.x + a0); o1.y = sigm_f(xr0.y + a1);
    o1.z = sigm_f(xr0.z + a2); o1.w = sigm_f(xr0.w + a3);
    o2.x = sigm_f(xr1.x + a4); o2.y = sigm_f(xr1.y + a5);
    o2.z = sigm_f(xr1.z + a6); o2.w = sigm_f(xr1.w + a7);
    out[(size_t)d * 8 + fi * 2]     = o1;
    out[(size_t)d * 8 + fi * 2 + 1] = o2;
  }
}

extern "C" void kernel_launch(void* const* d_in, const int* in_sizes, int n_in,
                              void* d_out, int out_size, void* d_ws, size_t ws_size,
                              hipStream_t stream) {
  const int*   edge_index = (const int*)d_in[0];
  const int*   et    = (const int*)d_in[1];
  const float* emb   = (const float*)d_in[2];
  const float* W1    = (const float*)d_in[3];
  const float* root1 = (const float*)d_in[4];
  const float* b1    = (const float*)d_in[5];
  const float* W2    = (const float*)d_in[6];
  const float* root2 = (const float*)d_in[7];
  const float* b2    = (const float*)d_in[8];
  float* out = (float*)d_out;

  const int E = in_sizes[1];
  const int N = in_sizes[2] / D0;
  const int* src  = edge_index;
  const int* dstp = edge_index + E;

  char* ws = (char*)d_ws;
  size_t off_b = 0;
  auto alloc = [&](size_t bytes) { size_t o = off_b; off_b = (off_b + bytes + 255) & ~(size_t)255; return o; };
  size_t counts_off = alloc((size_t)N * RR * 4);
  int*   counts = (int*)(ws + counts_off);
  size_t cur_off = alloc((size_t)N * 4);
  int*   cur    = (int*)(ws + cur_off);
  size_t zero_span = cur_off - counts_off + (size_t)N * 4;   // counts+cur contiguous
  float* invc   = (float*)(ws + alloc((size_t)N * RR * 4));
  int*   countd = (int*)(ws + alloc((size_t)N * 4));
  int*   offs   = (int*)(ws + alloc((size_t)(N + 1) * 4));
  int*   bsum   = (int*)(ws + alloc((size_t)1024 * 4));
  int*   ssr    = (int*)(ws + alloc((size_t)E * 4));
  u16*   X1b    = (u16*)(ws + alloc((size_t)N * D1 * 2));
  float* xr1    = (float*)(ws + alloc((size_t)N * D1 * 4));
  float* xr2    = (float*)(ws + alloc((size_t)N * D2 * 4));
  u16*   BT1    = (u16*)(ws + alloc((size_t)(RR * D1 + D1) * D0 * 2));
  u16*   BT2    = (u16*)(ws + alloc((size_t)(RR * D2 + D2) * D1 * 2 + 8192)); // +pad for clamp
  u16*   Y      = (u16*)(ws + alloc((size_t)N * RR * D1 * 2));   // Y1; reused as Y2

  auto cdiv = [](size_t a, size_t b) { return (unsigned)((a + b - 1) / b); };

  const int NC1 = RR * D1 + D1, YC1 = RR * D1;  // 576 / 512
  const int NC2 = RR * D2 + D2, YC2 = RR * D2;  // 288 / 256
  const int NB = cdiv(N, 1024);

  const int nbCount = cdiv(E, 256);
  const int nbP1 = cdiv((size_t)NC1 * D0, 256);
  const int nbP2 = cdiv((size_t)NC2 * D1, 256);
  const int nbGemm1 = cdiv(N, 64);
  const int nbPerm = cdiv(E, 256);

  // 1. zero counts+cur (one contiguous memset)
  hipMemsetAsync(counts, 0, zero_span, stream);
  // 2. count + pack BT1 + pack BT2 (merged)
  prep_k<<<nbCount + nbP1 + nbP2, 256, 0, stream>>>(dstp, et, counts, E,
                                                    W1, root1, BT1, W2, root2, BT2,
                                                    nbCount, nbP1);
  // 3-5. invc + 3-stage scan
  invscan_k<<<NB, 256, 0, stream>>>(counts, invc, countd, bsum, N);
  scan2_k<<<1, 256, 0, stream>>>(bsum, NB);
  scan3_k<<<NB, 256, 0, stream>>>(countd, bsum, offs, N);
  // 6. gemm layer-1 + permute (merged, independent work overlapped)
  pg1_k<<<nbGemm1 + nbPerm, 256, 0, stream>>>(emb, BT1, b1, Y, xr1, N, NC1, YC1, nbGemm1,
                                              src, dstp, et, offs, cur, ssr, E);
  // 7. aggregate layer-1 (fused root+relu+bf16)
  agg1_k<<<cdiv(N, 4), 256, 0, stream>>>(offs, ssr, (const uint4*)Y, invc,
                                         (const float4*)xr1, (uint4*)X1b, N, E);
  // 8. gemm layer-2
  gemm_k<D1, false><<<cdiv(N, 64), 256, 0, stream>>>(X1b, BT2, b2, Y, xr2, N, NC2, YC2);
  // 9. aggregate layer-2 (fused root+sigmoid)
  agg2_k<<<cdiv(N, 4), 256, 0, stream>>>(offs, ssr, (const uint4*)Y, invc,
                                         (const float4*)xr2, (float4*)out, N, E);
}